// Round 1
// baseline (1424.270 us; speedup 1.0000x reference)
//
#include <hip/hip_runtime.h>
#include <hip/hip_bf16.h>

#define NN 8192
#define DD 1024
#define KK 16384  // 2*NN

using half8 = __attribute__((ext_vector_type(8))) _Float16;
using half4 = __attribute__((ext_vector_type(4))) _Float16;
using f32x4 = __attribute__((ext_vector_type(4))) float;

// ---- static device buffers (self-contained; do not rely on ws_size) ----
__device__ __align__(16) _Float16 g_gh[(size_t)NN * DD];        // gen fp16
__device__ __align__(16) _Float16 g_ph[(size_t)NN * DD];        // pos fp16
__device__ __align__(16) _Float16 g_vt[(size_t)DD * KK];        // VT[d][k]: k<NN pos, k>=NN gen
__device__ float g_gn[NN];
__device__ float g_pn[NN];
__device__ float g_datt[(size_t)NN * NN];                       // 268 MB
__device__ float g_drep[(size_t)NN * NN];                       // 268 MB (diag=1e30)
__device__ float4 g_statA[NN];                                  // (dmin, c0, c1, c2)
__device__ float4 g_statR[NN];                                  // (dmin, -c0, -c1, -c2)
__device__ __align__(16) _Float16 g_w[(size_t)NN * KK];         // combined weights, 256 MB

typedef const __attribute__((address_space(1))) void GV;
typedef __attribute__((address_space(3))) void LV;
__device__ inline void gload16(const void* g, void* l) {
    __builtin_amdgcn_global_load_lds((GV*)g, (LV*)l, 16, 0, 0);
}

// ---- prep: fp16 convert + row norms. b<NN: gen row, else pos row ----
__global__ __launch_bounds__(256) void k_conv(const float* __restrict__ gen,
                                              const float* __restrict__ pos) {
    int b = blockIdx.x;
    int r = b & (NN - 1);
    const float* src = (b < NN) ? gen : pos;
    _Float16* dsth = (b < NN) ? g_gh : g_ph;
    float* dstn = (b < NN) ? g_gn : g_pn;
    int t = threadIdx.x;
    const float4* s4 = (const float4*)(src + (size_t)r * DD);
    float4 x = s4[t];
    half4 h = {(_Float16)x.x, (_Float16)x.y, (_Float16)x.z, (_Float16)x.w};
    *(half4*)(dsth + (size_t)r * DD + t * 4) = h;
    float s = x.x * x.x + x.y * x.y + x.z * x.z + x.w * x.w;
#pragma unroll
    for (int off = 32; off; off >>= 1) s += __shfl_xor(s, off);
    __shared__ float red[4];
    if ((t & 63) == 0) red[t >> 6] = s;
    __syncthreads();
    if (t == 0) dstn[r] = red[0] + red[1] + red[2] + red[3];
}

// ---- prep: build VT[d][k] (fp16 transpose of pos then gen) ----
__global__ __launch_bounds__(256) void k_tr(const float* __restrict__ pos,
                                            const float* __restrict__ gen) {
    int jt = blockIdx.x;  // 0..127 (64 rows of source)
    int dt = blockIdx.y;  // 0..15  (64 cols of source)
    int z = blockIdx.z;   // 0: pos -> k base 0, 1: gen -> k base NN
    const float* src = z ? gen : pos;
    size_t cbase = z ? (size_t)NN : 0;
    __shared__ _Float16 tile[64][68];
    int t = threadIdx.x;
    int j0 = jt * 64, d0 = dt * 64;
#pragma unroll
    for (int p = 0; p < 4; p++) {
        int idx = t + p * 256;  // 0..1023
        int r = idx >> 4;       // source row (j) 0..63
        int c4 = idx & 15;      // float4 col
        float4 x = *(const float4*)(src + (size_t)(j0 + r) * DD + d0 + c4 * 4);
        tile[r][c4 * 4 + 0] = (_Float16)x.x;
        tile[r][c4 * 4 + 1] = (_Float16)x.y;
        tile[r][c4 * 4 + 2] = (_Float16)x.z;
        tile[r][c4 * 4 + 3] = (_Float16)x.w;
    }
    __syncthreads();
#pragma unroll
    for (int p = 0; p < 4; p++) {
        int idx = t + p * 256;
        int d = idx >> 4;   // 0..63
        int j4 = idx & 15;  // group of 4 j
        half4 h = {tile[j4 * 4 + 0][d], tile[j4 * 4 + 1][d],
                   tile[j4 * 4 + 2][d], tile[j4 * 4 + 3][d]};
        *(half4*)(g_vt + (size_t)(d0 + d) * KK + cbase + j0 + j4 * 4) = h;
    }
}

// ---- distance matrices: fp16 MFMA GEMM, 128x128 tile, BK=64 ----
__global__ __launch_bounds__(256) void k_qk(void) {
    // grid (64, 64, 2): z=0 att (gen x pos), z=1 rep (gen x gen)
    int id = blockIdx.y * 64 + blockIdx.x;
    id = (id & 7) * 512 + (id >> 3);  // XCD swizzle (4096 % 8 == 0, bijective)
    int rt = id >> 6, ct = id & 63;
    int rep = blockIdx.z;
    const _Float16* A = g_gh;
    const _Float16* B = rep ? g_gh : g_ph;
    const float* An = g_gn;
    const float* Bn = rep ? g_gn : g_pn;
    float* out = rep ? g_drep : g_datt;

    __shared__ _Float16 sA[128 * 64];
    __shared__ _Float16 sB[128 * 64];

    int t = threadIdx.x;
    int w = t >> 6, lane = t & 63;
    int wr = w >> 1, wc = w & 1;
    int srow = lane >> 3;  // 0..7 row within 8-row group
    int schk = lane & 7;   // 16B chunk within 128B row

    f32x4 acc[4][4] = {};

    for (int kt = 0; kt < DD / 64; ++kt) {
#pragma unroll
        for (int i = 0; i < 4; i++) {
            int lr = w * 32 + i * 8 + srow;  // local row 0..127
            const _Float16* gp = A + (size_t)(rt * 128 + lr) * DD + kt * 64 + schk * 8;
            gload16(gp, &sA[(w * 32 + i * 8) * 64]);
            const _Float16* gq = B + (size_t)(ct * 128 + lr) * DD + kt * 64 + schk * 8;
            gload16(gq, &sB[(w * 32 + i * 8) * 64]);
        }
        __syncthreads();
#pragma unroll
        for (int kk = 0; kk < 2; ++kk) {
            half8 a[4], b[4];
            int kb = kk * 32 + (lane >> 4) * 8;
#pragma unroll
            for (int m = 0; m < 4; m++)
                a[m] = *(const half8*)&sA[(wr * 64 + m * 16 + (lane & 15)) * 64 + kb];
#pragma unroll
            for (int n = 0; n < 4; n++)
                b[n] = *(const half8*)&sB[(wc * 64 + n * 16 + (lane & 15)) * 64 + kb];
#pragma unroll
            for (int m = 0; m < 4; m++)
#pragma unroll
                for (int n = 0; n < 4; n++)
                    acc[m][n] = __builtin_amdgcn_mfma_f32_16x16x32_f16(a[m], b[n], acc[m][n], 0, 0, 0);
        }
        __syncthreads();
    }

    int ci = lane & 15;
    int rbase = (lane >> 4) * 4;
#pragma unroll
    for (int m = 0; m < 4; m++) {
        int gi0 = rt * 128 + wr * 64 + m * 16 + rbase;
#pragma unroll
        for (int n = 0; n < 4; n++) {
            int gj = ct * 128 + wc * 64 + n * 16 + ci;
            float bn = Bn[gj];
#pragma unroll
            for (int r = 0; r < 4; r++) {
                int gi = gi0 + r;
                float dsq = An[gi] + bn - 2.0f * acc[m][n][r];
                float d = sqrtf(fmaxf(dsq, 0.0f));
                if (rep && gi == gj) d = 1e30f;
                out[(size_t)gi * NN + gj] = d;
            }
        }
    }
}

// ---- per-row dmin + softmax denominators -> coefficients ----
__global__ __launch_bounds__(256) void k_stats(const float* __restrict__ scales) {
    int b = blockIdx.x;  // 0..16383
    int i = b & (NN - 1);
    int rep = b >> 13;
    const float* drow = (rep ? g_drep : g_datt) + (size_t)i * NN;
    int t = threadIdx.x;
    const float4* r4 = (const float4*)drow;
    float v[32];
    float mn = 1e30f;
#pragma unroll
    for (int p = 0; p < 8; p++) {
        float4 x = r4[t + p * 256];
        v[p * 4 + 0] = x.x; v[p * 4 + 1] = x.y; v[p * 4 + 2] = x.z; v[p * 4 + 3] = x.w;
        mn = fminf(mn, fminf(fminf(x.x, x.y), fminf(x.z, x.w)));
    }
#pragma unroll
    for (int off = 32; off; off >>= 1) mn = fminf(mn, __shfl_xor(mn, off));
    __shared__ float red[4];
    __shared__ float redl[3][4];
    if ((t & 63) == 0) red[t >> 6] = mn;
    __syncthreads();
    mn = fminf(fminf(red[0], red[1]), fminf(red[2], red[3]));
    float s0 = 0.f, s1 = 0.f, s2 = 0.f;
#pragma unroll
    for (int k = 0; k < 32; k++) {
        float dd = v[k] - mn;  // >= 0 (diag 1e30 -> exp underflows to 0)
        s0 += __expf(dd * -50.0f);
        s1 += __expf(dd * -20.0f);
        s2 += __expf(dd * -5.0f);
    }
#pragma unroll
    for (int off = 32; off; off >>= 1) {
        s0 += __shfl_xor(s0, off);
        s1 += __shfl_xor(s1, off);
        s2 += __shfl_xor(s2, off);
    }
    if ((t & 63) == 0) {
        redl[0][t >> 6] = s0; redl[1][t >> 6] = s1; redl[2][t >> 6] = s2;
    }
    __syncthreads();
    if (t == 0) {
        float l0 = redl[0][0] + redl[0][1] + redl[0][2] + redl[0][3];
        float l1 = redl[1][0] + redl[1][1] + redl[1][2] + redl[1][3];
        float l2 = redl[2][0] + redl[2][1] + redl[2][2] + redl[2][3];
        float sgn = rep ? -1.0f : 1.0f;
        float c0 = sgn / (3.0f * fmaxf(scales[0], 1e-6f) * l0);
        float c1 = sgn / (3.0f * fmaxf(scales[1], 1e-6f) * l1);
        float c2 = sgn / (3.0f * fmaxf(scales[2], 1e-6f) * l2);
        float4 st = {mn, c0, c1, c2};
        if (rep) g_statR[i] = st; else g_statA[i] = st;
    }
}

// ---- combined weights W[i][k] fp16 (3 temps collapsed, rep negated) ----
__global__ __launch_bounds__(256) void k_wk(void) {
    int rep = blockIdx.x;  // 0/1
    int i = blockIdx.y;    // row
    const float* drow = (rep ? g_drep : g_datt) + (size_t)i * NN;
    float4 st = rep ? g_statR[i] : g_statA[i];
    _Float16* wrow = g_w + (size_t)i * KK + (size_t)rep * NN;
    int t = threadIdx.x;
    const float4* r4 = (const float4*)drow;
#pragma unroll
    for (int p = 0; p < 8; p++) {
        int idx = t + p * 256;
        float4 x = r4[idx];
        float xs[4] = {x.x, x.y, x.z, x.w};
        half4 h;
#pragma unroll
        for (int q = 0; q < 4; q++) {
            float dd = st.x - xs[q];  // <= 0
            float wv = st.y * __expf(dd * 50.0f) + st.z * __expf(dd * 20.0f) +
                       st.w * __expf(dd * 5.0f);
            h[q] = (_Float16)wv;
        }
        *(half4*)(wrow + idx * 4) = h;
    }
}

// ---- out = W @ VT^T : M=8192, N=1024, K=16384, fp32 out ----
__global__ __launch_bounds__(256) void k_gemm(float* __restrict__ out) {
    int rt = blockIdx.y;  // 0..63 row tile
    int ct = blockIdx.x;  // 0..7  dcol tile
    __shared__ _Float16 sA[128 * 64];
    __shared__ _Float16 sB[128 * 64];
    int t = threadIdx.x;
    int w = t >> 6, lane = t & 63;
    int wr = w >> 1, wc = w & 1;
    int srow = lane >> 3, schk = lane & 7;

    f32x4 acc[4][4] = {};

    for (int kt = 0; kt < KK / 64; ++kt) {
#pragma unroll
        for (int i = 0; i < 4; i++) {
            int lr = w * 32 + i * 8 + srow;
            const _Float16* gp = g_w + (size_t)(rt * 128 + lr) * KK + kt * 64 + schk * 8;
            gload16(gp, &sA[(w * 32 + i * 8) * 64]);
            const _Float16* gq = g_vt + (size_t)(ct * 128 + lr) * KK + kt * 64 + schk * 8;
            gload16(gq, &sB[(w * 32 + i * 8) * 64]);
        }
        __syncthreads();
#pragma unroll
        for (int kk = 0; kk < 2; ++kk) {
            half8 a[4], b[4];
            int kb = kk * 32 + (lane >> 4) * 8;
#pragma unroll
            for (int m = 0; m < 4; m++)
                a[m] = *(const half8*)&sA[(wr * 64 + m * 16 + (lane & 15)) * 64 + kb];
#pragma unroll
            for (int n = 0; n < 4; n++)
                b[n] = *(const half8*)&sB[(wc * 64 + n * 16 + (lane & 15)) * 64 + kb];
#pragma unroll
            for (int m = 0; m < 4; m++)
#pragma unroll
                for (int n = 0; n < 4; n++)
                    acc[m][n] = __builtin_amdgcn_mfma_f32_16x16x32_f16(a[m], b[n], acc[m][n], 0, 0, 0);
        }
        __syncthreads();
    }

    int ci = lane & 15;
    int rbase = (lane >> 4) * 4;
#pragma unroll
    for (int m = 0; m < 4; m++) {
#pragma unroll
        for (int n = 0; n < 4; n++) {
            int gj = ct * 128 + wc * 64 + n * 16 + ci;
#pragma unroll
            for (int r = 0; r < 4; r++) {
                int gi = rt * 128 + wr * 64 + m * 16 + rbase + r;
                out[(size_t)gi * DD + gj] = acc[m][n][r];
            }
        }
    }
}

extern "C" void kernel_launch(void* const* d_in, const int* in_sizes, int n_in,
                              void* d_out, int out_size, void* d_ws, size_t ws_size,
                              hipStream_t stream) {
    (void)in_sizes; (void)n_in; (void)d_ws; (void)ws_size; (void)out_size;
    const float* gen = (const float*)d_in[0];
    const float* pos = (const float*)d_in[1];
    const float* scales = (const float*)d_in[2];

    k_conv<<<dim3(2 * NN), 256, 0, stream>>>(gen, pos);
    k_tr<<<dim3(128, 16, 2), 256, 0, stream>>>(pos, gen);
    k_qk<<<dim3(64, 64, 2), 256, 0, stream>>>();
    k_stats<<<dim3(2 * NN), 256, 0, stream>>>(scales);
    k_wk<<<dim3(2, NN), 256, 0, stream>>>();
    k_gemm<<<dim3(8, 64), 256, 0, stream>>>((float*)d_out);
}

// Round 2
// 925.365 us; speedup vs baseline: 1.5391x; 1.5391x over previous
//
#include <hip/hip_runtime.h>
#include <hip/hip_bf16.h>

#define NN 8192
#define DD 1024
#define KK 16384  // 2*NN

using half8 = __attribute__((ext_vector_type(8))) _Float16;
using half4 = __attribute__((ext_vector_type(4))) _Float16;
using f32x4 = __attribute__((ext_vector_type(4))) float;

// ---- static device buffers ----
__device__ __align__(16) _Float16 g_gh[(size_t)NN * DD];   // gen fp16
__device__ __align__(16) _Float16 g_ph[(size_t)NN * DD];   // pos fp16
__device__ __align__(16) _Float16 g_vt[(size_t)DD * KK];   // VT[d][k]: k<NN pos, k>=NN gen
__device__ float g_gn[NN];
__device__ float g_pn[NN];
__device__ float g_datt[(size_t)NN * NN];                  // 268 MB
__device__ float g_drep[(size_t)NN * NN];                  // 268 MB (diag=1e30)
__device__ __align__(16) _Float16 g_w[(size_t)NN * KK];    // combined weights, 256 MB
__device__ float g_part[2 * (size_t)NN * DD];              // split-K partials, 64 MB

typedef const __attribute__((address_space(1))) void GV;
typedef __attribute__((address_space(3))) void LV;
__device__ inline void gload16(const void* g, void* l) {
    __builtin_amdgcn_global_load_lds((GV*)g, (LV*)l, 16, 0, 0);
}

// ---- prep: fp16 convert + row norms ----
__global__ __launch_bounds__(256) void k_conv(const float* __restrict__ gen,
                                              const float* __restrict__ pos) {
    int b = blockIdx.x;
    int r = b & (NN - 1);
    const float* src = (b < NN) ? gen : pos;
    _Float16* dsth = (b < NN) ? g_gh : g_ph;
    float* dstn = (b < NN) ? g_gn : g_pn;
    int t = threadIdx.x;
    const float4* s4 = (const float4*)(src + (size_t)r * DD);
    float4 x = s4[t];
    half4 h = {(_Float16)x.x, (_Float16)x.y, (_Float16)x.z, (_Float16)x.w};
    *(half4*)(dsth + (size_t)r * DD + t * 4) = h;
    float s = x.x * x.x + x.y * x.y + x.z * x.z + x.w * x.w;
#pragma unroll
    for (int off = 32; off; off >>= 1) s += __shfl_xor(s, off);
    __shared__ float red[4];
    if ((t & 63) == 0) red[t >> 6] = s;
    __syncthreads();
    if (t == 0) dstn[r] = red[0] + red[1] + red[2] + red[3];
}

// ---- prep: build VT[d][k] ----
__global__ __launch_bounds__(256) void k_tr(const float* __restrict__ pos,
                                            const float* __restrict__ gen) {
    int jt = blockIdx.x;  // 0..127
    int dt = blockIdx.y;  // 0..15
    int z = blockIdx.z;   // 0: pos, 1: gen
    const float* src = z ? gen : pos;
    size_t cbase = z ? (size_t)NN : 0;
    __shared__ _Float16 tile[64][68];
    int t = threadIdx.x;
    int j0 = jt * 64, d0 = dt * 64;
#pragma unroll
    for (int p = 0; p < 4; p++) {
        int idx = t + p * 256;
        int r = idx >> 4;
        int c4 = idx & 15;
        float4 x = *(const float4*)(src + (size_t)(j0 + r) * DD + d0 + c4 * 4);
        tile[r][c4 * 4 + 0] = (_Float16)x.x;
        tile[r][c4 * 4 + 1] = (_Float16)x.y;
        tile[r][c4 * 4 + 2] = (_Float16)x.z;
        tile[r][c4 * 4 + 3] = (_Float16)x.w;
    }
    __syncthreads();
#pragma unroll
    for (int p = 0; p < 4; p++) {
        int idx = t + p * 256;
        int d = idx >> 4;
        int j4 = idx & 15;
        half4 h = {tile[j4 * 4 + 0][d], tile[j4 * 4 + 1][d],
                   tile[j4 * 4 + 2][d], tile[j4 * 4 + 3][d]};
        *(half4*)(g_vt + (size_t)(d0 + d) * KK + cbase + j0 + j4 * 4) = h;
    }
}

// ==== 256x256 MFMA GEMM core, BK=32, 4-slot LDS ring, counted vmcnt ====
// LDS: sA ring 4 x 16KB, sB ring 4 x 16KB = 128 KiB dynamic.
// Rows are 64B (BK=32 fp16) -> b128 frag reads hit the 8-lane/granule floor
// with NO swizzle; global_load_lds stays linear (rule #21 satisfied).
__device__ inline void stage_tile(const _Float16* __restrict__ P, size_t ldk,
                                  int row0, int kcol0, _Float16* slot,
                                  int w, int lane) {
    int cph = lane & 3;                 // 16B chunk within 64B row
    int rbase = w * 16 + (lane >> 2);   // 0..127
#pragma unroll
    for (int j = 0; j < 2; ++j) {
        int row = j * 128 + rbase;
        gload16(P + (size_t)(row0 + row) * ldk + kcol0 + cph * 8,
                slot + (size_t)(j * 512 + w * 64) * 8);
    }
}

template <int LDK>
__device__ inline void gemm_core(const _Float16* __restrict__ A,
                                 const _Float16* __restrict__ B,
                                 int arow0, int brow0, int kcol0, int ntiles,
                                 _Float16* lds, f32x4 acc[8][4]) {
    int t = threadIdx.x;
    int w = t >> 6, lane = t & 63;
    int wm = w >> 2, wn = w & 3;   // 2x4 wave grid; per-wave 128x64 output
    int q = lane >> 4, li = lane & 15;
    _Float16* sA = lds;
    _Float16* sB = lds + 4 * 8192;

    // prologue: stage tiles 0,1,2 (12 loads/thread)
#pragma unroll
    for (int p = 0; p < 3; ++p) {
        stage_tile(A, LDK, arow0, kcol0 + p * 32, sA + p * 8192, w, lane);
        stage_tile(B, LDK, brow0, kcol0 + p * 32, sB + p * 8192, w, lane);
    }
    asm volatile("s_waitcnt vmcnt(8)" ::: "memory");  // tile 0 arrived
    __builtin_amdgcn_s_barrier();

    for (int kt = 0; kt < ntiles; ++kt) {
        int rb = kt & 3;
        const _Float16* a_ = sA + rb * 8192 + (wm * 128) * 32 + q * 8;
        const _Float16* b_ = sB + rb * 8192 + (wn * 64) * 32 + q * 8;
        half8 af[4], bf[4];
        // ---- phase 0: stage A(kt+3) | read a[0..3], b[0..3] | MFMA m0..3 ----
        if (kt + 3 < ntiles)
            stage_tile(A, LDK, arow0, kcol0 + (kt + 3) * 32,
                       sA + ((kt + 3) & 3) * 8192, w, lane);
#pragma unroll
        for (int m = 0; m < 4; ++m) af[m] = *(const half8*)(a_ + (m * 16 + li) * 32);
#pragma unroll
        for (int n = 0; n < 4; ++n) bf[n] = *(const half8*)(b_ + (n * 16 + li) * 32);
        __builtin_amdgcn_s_barrier();
        __builtin_amdgcn_s_setprio(1);
#pragma unroll
        for (int m = 0; m < 4; ++m)
#pragma unroll
            for (int n = 0; n < 4; ++n)
                acc[m][n] = __builtin_amdgcn_mfma_f32_16x16x32_f16(af[m], bf[n], acc[m][n], 0, 0, 0);
        __builtin_amdgcn_s_setprio(0);
        __builtin_amdgcn_s_barrier();
        // ---- phase 1: stage B(kt+3) | read a[4..7] (b held in regs) | MFMA m4..7 ----
        if (kt + 3 < ntiles)
            stage_tile(B, LDK, brow0, kcol0 + (kt + 3) * 32,
                       sB + ((kt + 3) & 3) * 8192, w, lane);
#pragma unroll
        for (int m = 0; m < 4; ++m) af[m] = *(const half8*)(a_ + ((m + 4) * 16 + li) * 32);
        __builtin_amdgcn_s_barrier();
        __builtin_amdgcn_s_setprio(1);
#pragma unroll
        for (int m = 0; m < 4; ++m)
#pragma unroll
            for (int n = 0; n < 4; ++n)
                acc[m + 4][n] = __builtin_amdgcn_mfma_f32_16x16x32_f16(af[m], bf[n], acc[m + 4][n], 0, 0, 0);
        __builtin_amdgcn_s_setprio(0);
        // ---- iter boundary: counted wait (tile kt+1 must have arrived) ----
        if (kt < ntiles - 1) {
            if (kt + 3 <= ntiles - 1)
                asm volatile("s_waitcnt vmcnt(8)" ::: "memory");
            else if (kt + 2 <= ntiles - 1)
                asm volatile("s_waitcnt vmcnt(4)" ::: "memory");
            else
                asm volatile("s_waitcnt vmcnt(0)" ::: "memory");
            __builtin_amdgcn_s_barrier();
        }
    }
}

// ---- distance matrices via the core ----
__global__ __launch_bounds__(512, 2) void k_qk2() {
    extern __shared__ _Float16 lds[];
    int id = blockIdx.y * 32 + blockIdx.x;   // 0..1023
    id = (id & 7) * 128 + (id >> 3);         // XCD swizzle (1024%8==0, bijective)
    int rt = id >> 5, ct = id & 31;
    int rep = blockIdx.z;
    const _Float16* A = g_gh;
    const _Float16* B = rep ? g_gh : g_ph;
    const float* An = g_gn;
    const float* Bn = rep ? g_gn : g_pn;
    float* outp = rep ? g_drep : g_datt;

    f32x4 acc[8][4] = {};
    gemm_core<DD>(A, B, rt * 256, ct * 256, 0, DD / 32, lds, acc);

    int t = threadIdx.x, w = t >> 6, lane = t & 63;
    int wm = w >> 2, wn = w & 3, q = lane >> 4, li = lane & 15;
    float bnv[4];
#pragma unroll
    for (int n = 0; n < 4; ++n) bnv[n] = Bn[ct * 256 + wn * 64 + n * 16 + li];
#pragma unroll
    for (int m = 0; m < 8; ++m) {
        int gi0 = rt * 256 + wm * 128 + m * 16 + q * 4;
#pragma unroll
        for (int r = 0; r < 4; ++r) {
            int gi = gi0 + r;
            float an = An[gi];
            float* orow = outp + (size_t)gi * NN;
#pragma unroll
            for (int n = 0; n < 4; ++n) {
                int gj = ct * 256 + wn * 64 + n * 16 + li;
                float dsq = an + bnv[n] - 2.0f * acc[m][n][r];
                float d = sqrtf(fmaxf(dsq, 0.0f));
                if (rep && gi == gj) d = 1e30f;
                orow[gj] = d;
            }
        }
    }
}

// ---- fused stats + weights: rows held in registers, one read of D ----
__global__ __launch_bounds__(256) void k_sw(const float* __restrict__ scales) {
    int i = blockIdx.x, t = threadIdx.x;
    const float4* ra = (const float4*)(g_datt + (size_t)i * NN);
    const float4* rr = (const float4*)(g_drep + (size_t)i * NN);
    float va[32], vr[32];
    float mna = 1e30f, mnr = 1e30f;
#pragma unroll
    for (int p = 0; p < 8; ++p) {
        float4 x = ra[t + p * 256];
        float4 y = rr[t + p * 256];
        va[p * 4 + 0] = x.x; va[p * 4 + 1] = x.y; va[p * 4 + 2] = x.z; va[p * 4 + 3] = x.w;
        vr[p * 4 + 0] = y.x; vr[p * 4 + 1] = y.y; vr[p * 4 + 2] = y.z; vr[p * 4 + 3] = y.w;
        mna = fminf(mna, fminf(fminf(x.x, x.y), fminf(x.z, x.w)));
        mnr = fminf(mnr, fminf(fminf(y.x, y.y), fminf(y.z, y.w)));
    }
#pragma unroll
    for (int off = 32; off; off >>= 1) {
        mna = fminf(mna, __shfl_xor(mna, off));
        mnr = fminf(mnr, __shfl_xor(mnr, off));
    }
    __shared__ float sm[2][4];
    __shared__ float ss[6][4];
    int wv = t >> 6;
    if ((t & 63) == 0) { sm[0][wv] = mna; sm[1][wv] = mnr; }
    __syncthreads();
    mna = fminf(fminf(sm[0][0], sm[0][1]), fminf(sm[0][2], sm[0][3]));
    mnr = fminf(fminf(sm[1][0], sm[1][1]), fminf(sm[1][2], sm[1][3]));
    float s0 = 0.f, s1 = 0.f, s2 = 0.f, s3 = 0.f, s4 = 0.f, s5 = 0.f;
#pragma unroll
    for (int k = 0; k < 32; ++k) {
        float da = va[k] - mna;
        s0 += __expf(da * -50.0f); s1 += __expf(da * -20.0f); s2 += __expf(da * -5.0f);
        float dr = vr[k] - mnr;
        s3 += __expf(dr * -50.0f); s4 += __expf(dr * -20.0f); s5 += __expf(dr * -5.0f);
    }
#pragma unroll
    for (int off = 32; off; off >>= 1) {
        s0 += __shfl_xor(s0, off); s1 += __shfl_xor(s1, off); s2 += __shfl_xor(s2, off);
        s3 += __shfl_xor(s3, off); s4 += __shfl_xor(s4, off); s5 += __shfl_xor(s5, off);
    }
    if ((t & 63) == 0) {
        ss[0][wv] = s0; ss[1][wv] = s1; ss[2][wv] = s2;
        ss[3][wv] = s3; ss[4][wv] = s4; ss[5][wv] = s5;
    }
    __syncthreads();
    float l0 = ss[0][0] + ss[0][1] + ss[0][2] + ss[0][3];
    float l1 = ss[1][0] + ss[1][1] + ss[1][2] + ss[1][3];
    float l2 = ss[2][0] + ss[2][1] + ss[2][2] + ss[2][3];
    float l3 = ss[3][0] + ss[3][1] + ss[3][2] + ss[3][3];
    float l4 = ss[4][0] + ss[4][1] + ss[4][2] + ss[4][3];
    float l5 = ss[5][0] + ss[5][1] + ss[5][2] + ss[5][3];
    float i0 = 1.0f / (3.0f * fmaxf(scales[0], 1e-6f));
    float i1 = 1.0f / (3.0f * fmaxf(scales[1], 1e-6f));
    float i2 = 1.0f / (3.0f * fmaxf(scales[2], 1e-6f));
    float ca0 = i0 / l0, ca1 = i1 / l1, ca2 = i2 / l2;
    float cr0 = -i0 / l3, cr1 = -i1 / l4, cr2 = -i2 / l5;
    _Float16* wa = g_w + (size_t)i * KK;
    _Float16* wr = wa + NN;
#pragma unroll
    for (int p = 0; p < 8; ++p) {
        half4 ha, hr;
#pragma unroll
        for (int qq = 0; qq < 4; ++qq) {
            float da = va[p * 4 + qq] - mna;
            ha[qq] = (_Float16)(ca0 * __expf(da * -50.0f) + ca1 * __expf(da * -20.0f) +
                                ca2 * __expf(da * -5.0f));
            float dr = vr[p * 4 + qq] - mnr;
            hr[qq] = (_Float16)(cr0 * __expf(dr * -50.0f) + cr1 * __expf(dr * -20.0f) +
                                cr2 * __expf(dr * -5.0f));
        }
        *(half4*)(wa + (size_t)(t + p * 256) * 4) = ha;
        *(half4*)(wr + (size_t)(t + p * 256) * 4) = hr;
    }
}

// ---- out_partial[z] = W[:, zK/2:(z+1)K/2] @ VT^T slice : split-K=2 ----
__global__ __launch_bounds__(512, 2) void k_gemm2() {
    extern __shared__ _Float16 lds[];
    int id = blockIdx.y * 4 + blockIdx.x;  // 0..127
    id = (id & 7) * 16 + (id >> 3);        // XCD swizzle (128%8==0)
    int rt = id >> 2, ct = id & 3;
    int z = blockIdx.z;
    f32x4 acc[8][4] = {};
    gemm_core<KK>(g_w, g_vt, rt * 256, ct * 256, z * (KK / 2), (KK / 2) / 32, lds, acc);
    float* outp = g_part + (size_t)z * NN * DD;
    int t = threadIdx.x, w = t >> 6, lane = t & 63;
    int wm = w >> 2, wn = w & 3, q = lane >> 4, li = lane & 15;
#pragma unroll
    for (int m = 0; m < 8; ++m) {
#pragma unroll
        for (int r = 0; r < 4; ++r) {
            int gi = rt * 256 + wm * 128 + m * 16 + q * 4 + r;
            float* orow = outp + (size_t)gi * DD;
#pragma unroll
            for (int n = 0; n < 4; ++n) {
                int gj = ct * 256 + wn * 64 + n * 16 + li;
                orow[gj] = acc[m][n][r];
            }
        }
    }
}

__global__ __launch_bounds__(256) void k_red(float* __restrict__ out) {
    size_t base = (size_t)blockIdx.x * 256 + threadIdx.x;
    const float4* p0 = (const float4*)g_part;
    const float4* p1 = (const float4*)(g_part + (size_t)NN * DD);
    float4* o4 = (float4*)out;
#pragma unroll
    for (int p = 0; p < 4; ++p) {
        size_t idx = base + (size_t)p * 524288;
        float4 a = p0[idx], b = p1[idx];
        float4 c = {a.x + b.x, a.y + b.y, a.z + b.z, a.w + b.w};
        o4[idx] = c;
    }
}

extern "C" void kernel_launch(void* const* d_in, const int* in_sizes, int n_in,
                              void* d_out, int out_size, void* d_ws, size_t ws_size,
                              hipStream_t stream) {
    (void)in_sizes; (void)n_in; (void)d_ws; (void)ws_size; (void)out_size;
    const float* gen = (const float*)d_in[0];
    const float* pos = (const float*)d_in[1];
    const float* scales = (const float*)d_in[2];

    hipFuncSetAttribute((const void*)k_qk2, hipFuncAttributeMaxDynamicSharedMemorySize, 131072);
    hipFuncSetAttribute((const void*)k_gemm2, hipFuncAttributeMaxDynamicSharedMemorySize, 131072);

    k_conv<<<dim3(2 * NN), 256, 0, stream>>>(gen, pos);
    k_tr<<<dim3(128, 16, 2), 256, 0, stream>>>(pos, gen);
    k_qk2<<<dim3(32, 32, 2), 512, 131072, stream>>>();
    k_sw<<<dim3(NN), 256, 0, stream>>>(scales);
    k_gemm2<<<dim3(4, 32, 2), 512, 131072, stream>>>();
    k_red<<<dim3(2048), 256, 0, stream>>>((float*)d_out);
}

// Round 3
// 918.881 us; speedup vs baseline: 1.5500x; 1.0071x over previous
//
#include <hip/hip_runtime.h>
#include <hip/hip_bf16.h>

#define NN 8192
#define DD 1024
#define KK 16384  // 2*NN

using half8 = __attribute__((ext_vector_type(8))) _Float16;
using half4 = __attribute__((ext_vector_type(4))) _Float16;
using f32x4 = __attribute__((ext_vector_type(4))) float;

// ---- static device buffers ----
__device__ __align__(16) _Float16 g_gh[(size_t)NN * DD];   // gen fp16
__device__ __align__(16) _Float16 g_ph[(size_t)NN * DD];   // pos fp16
__device__ __align__(16) _Float16 g_vt[(size_t)DD * KK];   // VT[d][k]: k<NN pos, k>=NN gen
__device__ float g_gn[NN];
__device__ float g_pn[NN];
__device__ float g_datt[(size_t)NN * NN];                  // 268 MB
__device__ float g_drep[(size_t)NN * NN];                  // 268 MB (diag=1e30)
__device__ __align__(16) _Float16 g_w[(size_t)NN * KK];    // combined weights, 256 MB
__device__ float g_part[2 * (size_t)NN * DD];              // split-K partials, 64 MB

typedef const __attribute__((address_space(1))) void GV;
typedef __attribute__((address_space(3))) void LV;
__device__ inline void gload16(const void* g, void* l) {
    __builtin_amdgcn_global_load_lds((GV*)g, (LV*)l, 16, 0, 0);
}

// ---- prep: fp16 convert + row norms ----
__global__ __launch_bounds__(256) void k_conv(const float* __restrict__ gen,
                                              const float* __restrict__ pos) {
    int b = blockIdx.x;
    int r = b & (NN - 1);
    const float* src = (b < NN) ? gen : pos;
    _Float16* dsth = (b < NN) ? g_gh : g_ph;
    float* dstn = (b < NN) ? g_gn : g_pn;
    int t = threadIdx.x;
    const float4* s4 = (const float4*)(src + (size_t)r * DD);
    float4 x = s4[t];
    half4 h = {(_Float16)x.x, (_Float16)x.y, (_Float16)x.z, (_Float16)x.w};
    *(half4*)(dsth + (size_t)r * DD + t * 4) = h;
    float s = x.x * x.x + x.y * x.y + x.z * x.z + x.w * x.w;
#pragma unroll
    for (int off = 32; off; off >>= 1) s += __shfl_xor(s, off);
    __shared__ float red[4];
    if ((t & 63) == 0) red[t >> 6] = s;
    __syncthreads();
    if (t == 0) dstn[r] = red[0] + red[1] + red[2] + red[3];
}

// ---- prep: build VT[d][k] ----
__global__ __launch_bounds__(256) void k_tr(const float* __restrict__ pos,
                                            const float* __restrict__ gen) {
    int jt = blockIdx.x;  // 0..127
    int dt = blockIdx.y;  // 0..15
    int z = blockIdx.z;   // 0: pos, 1: gen
    const float* src = z ? gen : pos;
    size_t cbase = z ? (size_t)NN : 0;
    __shared__ _Float16 tile[64][68];
    int t = threadIdx.x;
    int j0 = jt * 64, d0 = dt * 64;
#pragma unroll
    for (int p = 0; p < 4; p++) {
        int idx = t + p * 256;
        int r = idx >> 4;
        int c4 = idx & 15;
        float4 x = *(const float4*)(src + (size_t)(j0 + r) * DD + d0 + c4 * 4);
        tile[r][c4 * 4 + 0] = (_Float16)x.x;
        tile[r][c4 * 4 + 1] = (_Float16)x.y;
        tile[r][c4 * 4 + 2] = (_Float16)x.z;
        tile[r][c4 * 4 + 3] = (_Float16)x.w;
    }
    __syncthreads();
#pragma unroll
    for (int p = 0; p < 4; p++) {
        int idx = t + p * 256;
        int d = idx >> 4;
        int j4 = idx & 15;
        half4 h = {tile[j4 * 4 + 0][d], tile[j4 * 4 + 1][d],
                   tile[j4 * 4 + 2][d], tile[j4 * 4 + 3][d]};
        *(half4*)(g_vt + (size_t)(d0 + d) * KK + cbase + j0 + j4 * 4) = h;
    }
}

// ==== 256x256 MFMA GEMM core, BK=32, 4-slot LDS ring, counted vmcnt ====
// LDS layout per slot: [row][chunk] with 64B rows (4x 16B chunks), but chunk
// is XOR-swizzled: global chunk c of row r lives at LDS chunk c ^ ((r>>1)&3).
// Swizzle is applied on the GLOBAL source address (global_load_lds dest must
// stay linear, rule #21) and identically on fragment reads. Result: each
// 16-lane quarter-wave frag read spreads 2 lanes/granule over all 8 granules
// (was 8-way on 2 granules).
__device__ inline void stage_tile(const _Float16* __restrict__ P, size_t ldk,
                                  int row0, int kcol0, _Float16* slot,
                                  int w, int lane) {
    int cph = lane & 3;                 // LDS 16B chunk this lane's data lands in
    int rbase = w * 16 + (lane >> 2);   // 0..127
    int csrc = cph ^ ((rbase >> 1) & 3);  // swizzled source chunk
#pragma unroll
    for (int j = 0; j < 2; ++j) {
        int row = j * 128 + rbase;
        gload16(P + (size_t)(row0 + row) * ldk + kcol0 + csrc * 8,
                slot + (size_t)(j * 512 + w * 64) * 8);
    }
}

template <int LDK>
__device__ inline void gemm_core(const _Float16* __restrict__ A,
                                 const _Float16* __restrict__ B,
                                 int arow0, int brow0, int kcol0, int ntiles,
                                 _Float16* lds, f32x4 acc[8][4]) {
    int t = threadIdx.x;
    int w = t >> 6, lane = t & 63;
    int wm = w >> 2, wn = w & 3;   // 2x4 wave grid; per-wave 128x64 output
    int q = lane >> 4, li = lane & 15;
    _Float16* sA = lds;
    _Float16* sB = lds + 4 * 8192;

    // per-thread swizzled fragment offsets (halves), hoisted out of the loop
    int offA[8], offB[4];
#pragma unroll
    for (int m = 0; m < 8; ++m) {
        int row = wm * 128 + m * 16 + li;
        offA[m] = row * 32 + (q ^ ((row >> 1) & 3)) * 8;
    }
#pragma unroll
    for (int n = 0; n < 4; ++n) {
        int row = wn * 64 + n * 16 + li;
        offB[n] = row * 32 + (q ^ ((row >> 1) & 3)) * 8;
    }

    // prologue: stage tiles 0,1,2 (12 loads/thread)
#pragma unroll
    for (int p = 0; p < 3; ++p) {
        stage_tile(A, LDK, arow0, kcol0 + p * 32, sA + p * 8192, w, lane);
        stage_tile(B, LDK, brow0, kcol0 + p * 32, sB + p * 8192, w, lane);
    }
    asm volatile("s_waitcnt vmcnt(8)" ::: "memory");  // tile 0 arrived
    __builtin_amdgcn_s_barrier();

    for (int kt = 0; kt < ntiles; ++kt) {
        int rb = kt & 3;
        const _Float16* a_ = sA + rb * 8192;
        const _Float16* b_ = sB + rb * 8192;
        half8 af[4], bf[4];
        // ---- phase 0: stage A(kt+3) | read a[0..3], b[0..3] | MFMA m0..3 ----
        if (kt + 3 < ntiles)
            stage_tile(A, LDK, arow0, kcol0 + (kt + 3) * 32,
                       sA + ((kt + 3) & 3) * 8192, w, lane);
#pragma unroll
        for (int m = 0; m < 4; ++m) af[m] = *(const half8*)(a_ + offA[m]);
#pragma unroll
        for (int n = 0; n < 4; ++n) bf[n] = *(const half8*)(b_ + offB[n]);
        __builtin_amdgcn_s_barrier();
        __builtin_amdgcn_s_setprio(1);
#pragma unroll
        for (int m = 0; m < 4; ++m)
#pragma unroll
            for (int n = 0; n < 4; ++n)
                acc[m][n] = __builtin_amdgcn_mfma_f32_16x16x32_f16(af[m], bf[n], acc[m][n], 0, 0, 0);
        __builtin_amdgcn_s_setprio(0);
        __builtin_amdgcn_s_barrier();
        // ---- phase 1: stage B(kt+3) | read a[4..7] (b held in regs) | MFMA m4..7 ----
        if (kt + 3 < ntiles)
            stage_tile(B, LDK, brow0, kcol0 + (kt + 3) * 32,
                       sB + ((kt + 3) & 3) * 8192, w, lane);
#pragma unroll
        for (int m = 0; m < 4; ++m) af[m] = *(const half8*)(a_ + offA[m + 4]);
        __builtin_amdgcn_s_barrier();
        __builtin_amdgcn_s_setprio(1);
#pragma unroll
        for (int m = 0; m < 4; ++m)
#pragma unroll
            for (int n = 0; n < 4; ++n)
                acc[m + 4][n] = __builtin_amdgcn_mfma_f32_16x16x32_f16(af[m], bf[n], acc[m + 4][n], 0, 0, 0);
        __builtin_amdgcn_s_setprio(0);
        // ---- iter boundary: counted wait (tile kt+1 must have arrived) ----
        if (kt < ntiles - 1) {
            if (kt + 3 <= ntiles - 1)
                asm volatile("s_waitcnt vmcnt(8)" ::: "memory");
            else if (kt + 2 <= ntiles - 1)
                asm volatile("s_waitcnt vmcnt(4)" ::: "memory");
            else
                asm volatile("s_waitcnt vmcnt(0)" ::: "memory");
            __builtin_amdgcn_s_barrier();
        }
    }
}

// ---- distance matrices via the core ----
__global__ __launch_bounds__(512, 2) void k_qk2() {
    extern __shared__ _Float16 lds[];
    int id = blockIdx.y * 32 + blockIdx.x;   // 0..1023
    id = (id & 7) * 128 + (id >> 3);         // XCD swizzle (1024%8==0, bijective)
    int rt = id >> 5, ct = id & 31;
    int rep = blockIdx.z;
    const _Float16* A = g_gh;
    const _Float16* B = rep ? g_gh : g_ph;
    const float* An = g_gn;
    const float* Bn = rep ? g_gn : g_pn;
    float* outp = rep ? g_drep : g_datt;

    f32x4 acc[8][4] = {};
    gemm_core<DD>(A, B, rt * 256, ct * 256, 0, DD / 32, lds, acc);

    int t = threadIdx.x, w = t >> 6, lane = t & 63;
    int wm = w >> 2, wn = w & 3, q = lane >> 4, li = lane & 15;
    float bnv[4];
#pragma unroll
    for (int n = 0; n < 4; ++n) bnv[n] = Bn[ct * 256 + wn * 64 + n * 16 + li];
#pragma unroll
    for (int m = 0; m < 8; ++m) {
        int gi0 = rt * 256 + wm * 128 + m * 16 + q * 4;
#pragma unroll
        for (int r = 0; r < 4; ++r) {
            int gi = gi0 + r;
            float an = An[gi];
            float* orow = outp + (size_t)gi * NN;
#pragma unroll
            for (int n = 0; n < 4; ++n) {
                int gj = ct * 256 + wn * 64 + n * 16 + li;
                float dsq = an + bnv[n] - 2.0f * acc[m][n][r];
                float d = sqrtf(fmaxf(dsq, 0.0f));
                if (rep && gi == gj) d = 1e30f;
                orow[gj] = d;
            }
        }
    }
}

// ---- fused stats + weights: rows held in registers, one read of D ----
__global__ __launch_bounds__(256) void k_sw(const float* __restrict__ scales) {
    int i = blockIdx.x, t = threadIdx.x;
    const float4* ra = (const float4*)(g_datt + (size_t)i * NN);
    const float4* rr = (const float4*)(g_drep + (size_t)i * NN);
    float va[32], vr[32];
    float mna = 1e30f, mnr = 1e30f;
#pragma unroll
    for (int p = 0; p < 8; ++p) {
        float4 x = ra[t + p * 256];
        float4 y = rr[t + p * 256];
        va[p * 4 + 0] = x.x; va[p * 4 + 1] = x.y; va[p * 4 + 2] = x.z; va[p * 4 + 3] = x.w;
        vr[p * 4 + 0] = y.x; vr[p * 4 + 1] = y.y; vr[p * 4 + 2] = y.z; vr[p * 4 + 3] = y.w;
        mna = fminf(mna, fminf(fminf(x.x, x.y), fminf(x.z, x.w)));
        mnr = fminf(mnr, fminf(fminf(y.x, y.y), fminf(y.z, y.w)));
    }
#pragma unroll
    for (int off = 32; off; off >>= 1) {
        mna = fminf(mna, __shfl_xor(mna, off));
        mnr = fminf(mnr, __shfl_xor(mnr, off));
    }
    __shared__ float sm[2][4];
    __shared__ float ss[6][4];
    int wv = t >> 6;
    if ((t & 63) == 0) { sm[0][wv] = mna; sm[1][wv] = mnr; }
    __syncthreads();
    mna = fminf(fminf(sm[0][0], sm[0][1]), fminf(sm[0][2], sm[0][3]));
    mnr = fminf(fminf(sm[1][0], sm[1][1]), fminf(sm[1][2], sm[1][3]));
    float s0 = 0.f, s1 = 0.f, s2 = 0.f, s3 = 0.f, s4 = 0.f, s5 = 0.f;
#pragma unroll
    for (int k = 0; k < 32; ++k) {
        float da = va[k] - mna;
        s0 += __expf(da * -50.0f); s1 += __expf(da * -20.0f); s2 += __expf(da * -5.0f);
        float dr = vr[k] - mnr;
        s3 += __expf(dr * -50.0f); s4 += __expf(dr * -20.0f); s5 += __expf(dr * -5.0f);
    }
#pragma unroll
    for (int off = 32; off; off >>= 1) {
        s0 += __shfl_xor(s0, off); s1 += __shfl_xor(s1, off); s2 += __shfl_xor(s2, off);
        s3 += __shfl_xor(s3, off); s4 += __shfl_xor(s4, off); s5 += __shfl_xor(s5, off);
    }
    if ((t & 63) == 0) {
        ss[0][wv] = s0; ss[1][wv] = s1; ss[2][wv] = s2;
        ss[3][wv] = s3; ss[4][wv] = s4; ss[5][wv] = s5;
    }
    __syncthreads();
    float l0 = ss[0][0] + ss[0][1] + ss[0][2] + ss[0][3];
    float l1 = ss[1][0] + ss[1][1] + ss[1][2] + ss[1][3];
    float l2 = ss[2][0] + ss[2][1] + ss[2][2] + ss[2][3];
    float l3 = ss[3][0] + ss[3][1] + ss[3][2] + ss[3][3];
    float l4 = ss[4][0] + ss[4][1] + ss[4][2] + ss[4][3];
    float l5 = ss[5][0] + ss[5][1] + ss[5][2] + ss[5][3];
    float i0 = 1.0f / (3.0f * fmaxf(scales[0], 1e-6f));
    float i1 = 1.0f / (3.0f * fmaxf(scales[1], 1e-6f));
    float i2 = 1.0f / (3.0f * fmaxf(scales[2], 1e-6f));
    float ca0 = i0 / l0, ca1 = i1 / l1, ca2 = i2 / l2;
    float cr0 = -i0 / l3, cr1 = -i1 / l4, cr2 = -i2 / l5;
    _Float16* wa = g_w + (size_t)i * KK;
    _Float16* wr = wa + NN;
#pragma unroll
    for (int p = 0; p < 8; ++p) {
        half4 ha, hr;
#pragma unroll
        for (int qq = 0; qq < 4; ++qq) {
            float da = va[p * 4 + qq] - mna;
            ha[qq] = (_Float16)(ca0 * __expf(da * -50.0f) + ca1 * __expf(da * -20.0f) +
                                ca2 * __expf(da * -5.0f));
            float dr = vr[p * 4 + qq] - mnr;
            hr[qq] = (_Float16)(cr0 * __expf(dr * -50.0f) + cr1 * __expf(dr * -20.0f) +
                                cr2 * __expf(dr * -5.0f));
        }
        *(half4*)(wa + (size_t)(t + p * 256) * 4) = ha;
        *(half4*)(wr + (size_t)(t + p * 256) * 4) = hr;
    }
}

// ---- out_partial[z] = W[:, zK/2:(z+1)K/2] @ VT^T slice : split-K=2 ----
__global__ __launch_bounds__(512, 2) void k_gemm2() {
    extern __shared__ _Float16 lds[];
    int id = blockIdx.y * 4 + blockIdx.x;  // 0..127
    id = (id & 7) * 16 + (id >> 3);        // XCD swizzle (128%8==0)
    int rt = id >> 2, ct = id & 3;
    int z = blockIdx.z;
    f32x4 acc[8][4] = {};
    gemm_core<KK>(g_w, g_vt, rt * 256, ct * 256, z * (KK / 2), (KK / 2) / 32, lds, acc);
    float* outp = g_part + (size_t)z * NN * DD;
    int t = threadIdx.x, w = t >> 6, lane = t & 63;
    int wm = w >> 2, wn = w & 3, q = lane >> 4, li = lane & 15;
#pragma unroll
    for (int m = 0; m < 8; ++m) {
#pragma unroll
        for (int r = 0; r < 4; ++r) {
            int gi = rt * 256 + wm * 128 + m * 16 + q * 4 + r;
            float* orow = outp + (size_t)gi * DD;
#pragma unroll
            for (int n = 0; n < 4; ++n) {
                int gj = ct * 256 + wn * 64 + n * 16 + li;
                orow[gj] = acc[m][n][r];
            }
        }
    }
}

__global__ __launch_bounds__(256) void k_red(float* __restrict__ out) {
    size_t base = (size_t)blockIdx.x * 256 + threadIdx.x;
    const float4* p0 = (const float4*)g_part;
    const float4* p1 = (const float4*)(g_part + (size_t)NN * DD);
    float4* o4 = (float4*)out;
#pragma unroll
    for (int p = 0; p < 4; ++p) {
        size_t idx = base + (size_t)p * 524288;
        float4 a = p0[idx], b = p1[idx];
        float4 c = {a.x + b.x, a.y + b.y, a.z + b.z, a.w + b.w};
        o4[idx] = c;
    }
}

extern "C" void kernel_launch(void* const* d_in, const int* in_sizes, int n_in,
                              void* d_out, int out_size, void* d_ws, size_t ws_size,
                              hipStream_t stream) {
    (void)in_sizes; (void)n_in; (void)d_ws; (void)ws_size; (void)out_size;
    const float* gen = (const float*)d_in[0];
    const float* pos = (const float*)d_in[1];
    const float* scales = (const float*)d_in[2];

    hipFuncSetAttribute((const void*)k_qk2, hipFuncAttributeMaxDynamicSharedMemorySize, 131072);
    hipFuncSetAttribute((const void*)k_gemm2, hipFuncAttributeMaxDynamicSharedMemorySize, 131072);

    k_conv<<<dim3(2 * NN), 256, 0, stream>>>(gen, pos);
    k_tr<<<dim3(128, 16, 2), 256, 0, stream>>>(pos, gen);
    k_qk2<<<dim3(32, 32, 2), 512, 131072, stream>>>();
    k_sw<<<dim3(NN), 256, 0, stream>>>(scales);
    k_gemm2<<<dim3(4, 32, 2), 512, 131072, stream>>>();
    k_red<<<dim3(2048), 256, 0, stream>>>((float*)d_out);
}